// Round 6
// baseline (104.001 us; speedup 1.0000x reference)
//
#include <hip/hip_runtime.h>
#include <hip/hip_bf16.h>

typedef __attribute__((ext_vector_type(8))) short bf16x8;
typedef __attribute__((ext_vector_type(4))) float f32x4;

__device__ __forceinline__ unsigned int pk2(float a, float b) {
  union { __hip_bfloat162 h; unsigned int u; } cv;
  cv.h = __float22bfloat162_rn(make_float2(a, b));   // v_cvt_pk_bf16_f32
  return cv.u;
}
__device__ __forceinline__ unsigned short f2bf(float f) {
  unsigned int u = __float_as_uint(f);
  u += 0x7FFFu + ((u >> 16) & 1u);
  return (unsigned short)(u >> 16);
}

// qw[n][e] = scale * sum_d query[n][d] * W[d][e]   (N=64, E=256), stored bf16
__global__ void __launch_bounds__(256) qw_kernel(const float* __restrict__ q,
                                                 const float* __restrict__ W,
                                                 unsigned short* __restrict__ qw) {
  int n = blockIdx.x, e = threadIdx.x;
  float acc = 0.f;
  #pragma unroll 8
  for (int d = 0; d < 256; ++d) acc = fmaf(q[n * 256 + d], W[d * 256 + e], acc);
  qw[n * 256 + e] = f2bf(acc * 0.0625f);  // scale = 256^-0.5
}

// 1024 blocks x 512 threads; block handles batches b and b+1024 with
// cross-batch prefetch (T14): batch-1's first half-x loads fly under batch-0 compute.
__global__ void __launch_bounds__(512, 6) cross_main(
    const float* __restrict__ x, const float* __restrict__ value,
    const unsigned short* __restrict__ qw, float* __restrict__ out) {

  __shared__ __align__(16) unsigned short lds_x[64 * 268];       // x[f][e] bf16, row = 536 B
  __shared__ __align__(16) unsigned char  lds_pool[64 * 68 * 4]; // att (f32) then aw (bf16)

  float* lds_att = (float*)lds_pool;                  // [64][68] f32: GEMM1 -> entmax
  unsigned short* lds_aw = (unsigned short*)lds_pool; // [64][72] bf16: entmax -> GEMM2

  const int t = threadIdx.x;
  const int l = t & 63;
  const int w = t >> 6;
  const int l15 = l & 15, l4 = l >> 4;

  // ---- phase lambdas (bit-identical to R5 datapath) ----
  auto stage_unit = [&](int u, float4 v0, float4 v1) {   // u: 8-float unit 0..2047
    int f = u >> 5, c8 = u & 31;
    char* dst = (char*)lds_x + f * 536 + c8 * 16;
    *(uint2*)dst       = make_uint2(pk2(v0.x, v0.y), pk2(v0.z, v0.w));
    *(uint2*)(dst + 8) = make_uint2(pk2(v1.x, v1.y), pk2(v1.z, v1.w));
  };

  auto gemm1 = [&]() {
    int nt = w >> 1, ft0 = (w & 1) * 2;
    f32x4 acc0 = {0.f, 0.f, 0.f, 0.f}, acc1 = {0.f, 0.f, 0.f, 0.f};
    const unsigned short* qa = qw + (nt * 16 + l15) * 256 + l4 * 8;
    const char* rb0 = (const char*)lds_x + (ft0 * 16 + l15) * 536 + l4 * 16;
    const char* rb1 = rb0 + 16 * 536;
    #pragma unroll
    for (int kc = 0; kc < 8; ++kc) {
      union BF { uint2 d[2]; bf16x8 v; };
      bf16x8 a = *(const bf16x8*)(qa + kc * 32);
      BF b0, b1;
      b0.d[0] = *(const uint2*)(rb0 + kc * 64);
      b0.d[1] = *(const uint2*)(rb0 + kc * 64 + 8);
      b1.d[0] = *(const uint2*)(rb1 + kc * 64);
      b1.d[1] = *(const uint2*)(rb1 + kc * 64 + 8);
      acc0 = __builtin_amdgcn_mfma_f32_16x16x32_bf16(a, b0.v, acc0, 0, 0, 0);
      acc1 = __builtin_amdgcn_mfma_f32_16x16x32_bf16(a, b1.v, acc1, 0, 0, 0);
    }
    int nrow = nt * 16 + 4 * l4;
    #pragma unroll
    for (int r = 0; r < 4; ++r) {
      lds_att[(nrow + r) * 68 + ft0 * 16 + l15]       = acc0[r];
      lds_att[(nrow + r) * 68 + (ft0 + 1) * 16 + l15] = acc1[r];
    }
  };

  auto entmax_phase = [&]() {
    int n = w * 8 + (l >> 3);
    int fb = (l & 7) * 8;
    f32x4 z0 = *(const f32x4*)&lds_att[n * 68 + fb];
    f32x4 z1 = *(const f32x4*)&lds_att[n * 68 + fb + 4];
    __syncthreads();                // att dead; aw may overwrite pool
    float z[8];
    #pragma unroll
    for (int k = 0; k < 4; ++k) { z[k] = z0[k] * 0.5f; z[k + 4] = z1[k] * 0.5f; }
    float m = fmaxf(fmaxf(fmaxf(z[0], z[1]), fmaxf(z[2], z[3])),
                    fmaxf(fmaxf(z[4], z[5]), fmaxf(z[6], z[7])));
    m = fmaxf(m, __shfl_xor(m, 1));
    m = fmaxf(m, __shfl_xor(m, 2));
    m = fmaxf(m, __shfl_xor(m, 4));
    float tau = m - 1.0f;           // Newton from bracket-lo: monotone from below
    #pragma unroll
    for (int it = 0; it < 12; ++it) {
      float s0 = 0.f, s1 = 0.f, q0 = 0.f, q1 = 0.f;
      #pragma unroll
      for (int k = 0; k < 4; ++k) {
        float d0 = fmaxf(z[k] - tau, 0.f);
        float d1 = fmaxf(z[k + 4] - tau, 0.f);
        s0 = fmaf(d0, d0, s0); q0 += d0;
        s1 = fmaf(d1, d1, s1); q1 += d1;
      }
      float s = s0 + s1, q = q0 + q1;
      s += __shfl_xor(s, 1); s += __shfl_xor(s, 2); s += __shfl_xor(s, 4);
      q += __shfl_xor(q, 1); q += __shfl_xor(q, 2); q += __shfl_xor(q, 4);
      tau += (s - 1.0f) * 0.5f * __builtin_amdgcn_rcpf(q);
    }
    float p[8]; float S = 0.f;
    #pragma unroll
    for (int k = 0; k < 8; ++k) { float d = fmaxf(z[k] - tau, 0.f); p[k] = d * d; S += p[k]; }
    S += __shfl_xor(S, 1); S += __shfl_xor(S, 2); S += __shfl_xor(S, 4);
    float invS = 1.0f / S;
    const float4* vg = (const float4*)(value + n * 64 + fb);
    float4 va = vg[0], vb = vg[1];
    uint4 pkv;
    pkv.x = pk2(p[0] * invS * va.x, p[1] * invS * va.y);
    pkv.y = pk2(p[2] * invS * va.z, p[3] * invS * va.w);
    pkv.z = pk2(p[4] * invS * vb.x, p[5] * invS * vb.y);
    pkv.w = pk2(p[6] * invS * vb.z, p[7] * invS * vb.w);
    *(uint4*)&lds_aw[n * 72 + fb] = pkv;
  };

  auto gemm2_store = [&](float* ob) {
    const int te0 = 2 * w;
    f32x4 acc[4][2];
    #pragma unroll
    for (int nt = 0; nt < 4; ++nt) {
      acc[nt][0] = (f32x4){0.f, 0.f, 0.f, 0.f};
      acc[nt][1] = (f32x4){0.f, 0.f, 0.f, 0.f};
    }
    #pragma unroll
    for (int kc = 0; kc < 2; ++kc) {
      bf16x8 a[4];
      #pragma unroll
      for (int nt = 0; nt < 4; ++nt)
        a[nt] = *(const bf16x8*)&lds_aw[(nt * 16 + l15) * 72 + kc * 32 + l4 * 8];
      const char* gp = (const char*)lds_x + (kc * 32 + l4 * 8) * 536 + (te0 * 16 + l15) * 2;
      #pragma unroll
      for (int j = 0; j < 2; ++j) {
        union { unsigned short u[8]; bf16x8 v; } bb;   // transposed gather (2-way, free)
        #pragma unroll
        for (int i = 0; i < 8; ++i)
          bb.u[i] = *(const unsigned short*)(gp + i * 536 + j * 32);
        #pragma unroll
        for (int nt = 0; nt < 4; ++nt)
          acc[nt][j] = __builtin_amdgcn_mfma_f32_16x16x32_bf16(a[nt], bb.v, acc[nt][j], 0, 0, 0);
      }
    }
    #pragma unroll
    for (int nt = 0; nt < 4; ++nt)
      #pragma unroll
      for (int j = 0; j < 2; ++j)
        #pragma unroll
        for (int r = 0; r < 4; ++r)
          ob[(nt * 16 + 4 * l4 + r) * 256 + (te0 + j) * 16 + l15] = __expf(acc[nt][j][r]);
  };

  // ================= batch 0 =================
  const size_t b0 = blockIdx.x, b1 = blockIdx.x + 1024;
  const float4* xg0 = (const float4*)(x + b0 * 16384);
  #pragma unroll
  for (int it = 0; it < 4; ++it) {
    int u = it * 512 + t;
    stage_unit(u, xg0[2 * u], xg0[2 * u + 1]);
  }
  // prefetch first half of x[b1] (units t and 512+t): lands under batch-0 compute
  const float4* xg1 = (const float4*)(x + b1 * 16384);
  float4 pre0 = xg1[2 * t], pre1 = xg1[2 * t + 1];
  float4 pre2 = xg1[2 * (512 + t)], pre3 = xg1[2 * (512 + t) + 1];
  __syncthreads();

  gemm1();
  __syncthreads();
  entmax_phase();
  __syncthreads();
  gemm2_store(out + b0 * 16384);
  __syncthreads();                      // lds_x / lds_aw dead

  // ================= batch 1 =================
  stage_unit(t, pre0, pre1);            // consume prefetched half
  stage_unit(512 + t, pre2, pre3);
  #pragma unroll
  for (int it = 2; it < 4; ++it) {      // remaining half, fresh loads
    int u = it * 512 + t;
    stage_unit(u, xg1[2 * u], xg1[2 * u + 1]);
  }
  __syncthreads();

  gemm1();
  __syncthreads();
  entmax_phase();
  __syncthreads();
  gemm2_store(out + b1 * 16384);
}

extern "C" void kernel_launch(void* const* d_in, const int* in_sizes, int n_in,
                              void* d_out, int out_size, void* d_ws, size_t ws_size,
                              hipStream_t stream) {
  const float* x     = (const float*)d_in[0];
  const float* W     = (const float*)d_in[1];
  const float* q     = (const float*)d_in[2];
  const float* value = (const float*)d_in[3];
  float* out = (float*)d_out;
  unsigned short* qw = (unsigned short*)d_ws;  // 64*256 bf16 = 32 KB scratch

  qw_kernel<<<dim3(64), dim3(256), 0, stream>>>(q, W, qw);
  cross_main<<<dim3(1024), dim3(512), 0, stream>>>(x, value, qw, out);
}

// Round 8
// 77.445 us; speedup vs baseline: 1.3429x; 1.3429x over previous
//
#include <hip/hip_runtime.h>
#include <hip/hip_bf16.h>

typedef __attribute__((ext_vector_type(8))) short bf16x8;
typedef __attribute__((ext_vector_type(4))) float f32x4;

__device__ __forceinline__ unsigned int pk2(float a, float b) {
  union { __hip_bfloat162 h; unsigned int u; } cv;
  cv.h = __float22bfloat162_rn(make_float2(a, b));   // v_cvt_pk_bf16_f32
  return cv.u;
}
__device__ __forceinline__ unsigned short f2bf(float f) {
  unsigned int u = __float_as_uint(f);
  u += 0x7FFFu + ((u >> 16) & 1u);
  return (unsigned short)(u >> 16);
}

// qw[n][e] = scale * sum_d query[n][d] * W[d][e]   (N=64, E=256), stored bf16
__global__ void __launch_bounds__(256) qw_kernel(const float* __restrict__ q,
                                                 const float* __restrict__ W,
                                                 unsigned short* __restrict__ qw) {
  int n = blockIdx.x, e = threadIdx.x;
  float acc = 0.f;
  #pragma unroll 8
  for (int d = 0; d < 256; ++d) acc = fmaf(q[n * 256 + d], W[d * 256 + e], acc);
  qw[n * 256 + e] = f2bf(acc * 0.0625f);  // scale = 256^-0.5
}

// One block per batch. 512 threads = 8 waves.
// R7: (1) staging loads fully ILP'd (8 in flight); (2) GEMM1 operand-swapped:
// D[f][n] = mfma(A=x, B=qw) -> att lives in accumulators, entmax in-register
// (in-lane 16 + shfl_xor 16/32), lds_att deleted, 4 barriers -> 2.
// Waves w and w+4 duplicate n-tile w&3 (bit-identical -> benign dup aw writes).
__global__ void __launch_bounds__(512, 6) cross_main(
    const float* __restrict__ x, const float* __restrict__ value,
    const unsigned short* __restrict__ qw, float* __restrict__ out) {

  __shared__ __align__(16) unsigned short lds_x[64 * 268];  // x[f][e] bf16, row = 536 B
  __shared__ __align__(16) unsigned short lds_aw[64 * 72];  // aw[n][f] bf16, row = 144 B

  const int t = threadIdx.x;
  const int b = blockIdx.x;
  const int l = t & 63;
  const int w = t >> 6;
  const int l15 = l & 15, l4 = l >> 4;
  const int nt = w & 3;

  // ---- stage x[b]: 8 loads in flight, then convert+write ----
  {
    const float4* xg = (const float4*)(x + (size_t)b * 16384);
    float4 v[8];
    #pragma unroll
    for (int it = 0; it < 4; ++it) {
      v[2 * it]     = xg[2 * (it * 512 + t)];
      v[2 * it + 1] = xg[2 * (it * 512 + t) + 1];
    }
    #pragma unroll
    for (int it = 0; it < 4; ++it) {
      int u = it * 512 + t;
      int f = u >> 5, c8 = u & 31;
      char* dst = (char*)lds_x + f * 536 + c8 * 16;
      *(uint2*)dst       = make_uint2(pk2(v[2*it].x, v[2*it].y), pk2(v[2*it].z, v[2*it].w));
      *(uint2*)(dst + 8) = make_uint2(pk2(v[2*it+1].x, v[2*it+1].y), pk2(v[2*it+1].z, v[2*it+1].w));
    }
  }
  __syncthreads();

  // ---- GEMM1 (in-register att): D[f][n], A = x (M=f), B = qw (N=n) ----
  f32x4 zz[4];   // f-tile tt: lane holds att[f=16*tt+4*l4+r][n=nt*16+l15]
  {
    #pragma unroll
    for (int tt = 0; tt < 4; ++tt) zz[tt] = (f32x4){0.f, 0.f, 0.f, 0.f};
    const unsigned short* qb = qw + (nt * 16 + l15) * 256 + l4 * 8;
    const char* xa = (const char*)lds_x + l15 * 536 + l4 * 16;
    #pragma unroll
    for (int kc = 0; kc < 8; ++kc) {
      bf16x8 bq = *(const bf16x8*)(qb + kc * 32);   // global, L1-resident
      #pragma unroll
      for (int tt = 0; tt < 4; ++tt) {
        union BF { uint2 d[2]; bf16x8 v; } af;
        const char* p = xa + tt * (16 * 536) + kc * 64;
        af.d[0] = *(const uint2*)p;
        af.d[1] = *(const uint2*)(p + 8);
        zz[tt] = __builtin_amdgcn_mfma_f32_16x16x32_bf16(af.v, bq, zz[tt], 0, 0, 0);
      }
    }
  }

  // ---- entmax15 in-register: row n = nt*16+l15, 16 f-values/lane ----
  {
    const int n = nt * 16 + l15;
    float z[16];
    #pragma unroll
    for (int tt = 0; tt < 4; ++tt)
      #pragma unroll
      for (int r = 0; r < 4; ++r) z[tt * 4 + r] = zz[tt][r] * 0.5f;

    float m = z[0];
    #pragma unroll
    for (int k = 1; k < 16; ++k) m = fmaxf(m, z[k]);
    m = fmaxf(m, __shfl_xor(m, 16));
    m = fmaxf(m, __shfl_xor(m, 32));

    float tau = m - 1.0f;     // Newton from bracket-lo: monotone from below
    #pragma unroll
    for (int it = 0; it < 12; ++it) {
      float s0 = 0.f, s1 = 0.f, q0 = 0.f, q1 = 0.f;
      #pragma unroll
      for (int k = 0; k < 8; ++k) {
        float d0 = fmaxf(z[k] - tau, 0.f);
        float d1 = fmaxf(z[k + 8] - tau, 0.f);
        s0 = fmaf(d0, d0, s0); q0 += d0;
        s1 = fmaf(d1, d1, s1); q1 += d1;
      }
      float s = s0 + s1, q = q0 + q1;
      s += __shfl_xor(s, 16); s += __shfl_xor(s, 32);
      q += __shfl_xor(q, 16); q += __shfl_xor(q, 32);
      tau += (s - 1.0f) * 0.5f * __builtin_amdgcn_rcpf(q);
    }

    float p[16]; float S = 0.f;
    #pragma unroll
    for (int k = 0; k < 16; ++k) { float d = fmaxf(z[k] - tau, 0.f); p[k] = d * d; S += p[k]; }
    S += __shfl_xor(S, 16); S += __shfl_xor(S, 32);
    float invS = 1.0f / S;

    #pragma unroll
    for (int tt = 0; tt < 4; ++tt) {     // f = 16*tt + 4*l4 + r
      float4 vv = *(const float4*)(value + n * 64 + tt * 16 + l4 * 4);
      uint2 pkd = make_uint2(pk2(p[tt*4] * invS * vv.x,   p[tt*4+1] * invS * vv.y),
                             pk2(p[tt*4+2] * invS * vv.z, p[tt*4+3] * invS * vv.w));
      *(uint2*)&lds_aw[n * 72 + tt * 16 + l4 * 4] = pkd;   // dup write from w and w+4: identical
    }
  }
  __syncthreads();

  // ---- out[n][e] = exp( sum_f aw[n][f] * x[f][e] )  (M=n, N=e, K=f) ----
  // Wave w owns e-tiles {2w,2w+1}, all 4 n-tiles; gather 2-way (free) at stride 536.
  {
    const int te0 = 2 * w;
    f32x4 acc[4][2];
    #pragma unroll
    for (int nt2 = 0; nt2 < 4; ++nt2) {
      acc[nt2][0] = (f32x4){0.f, 0.f, 0.f, 0.f};
      acc[nt2][1] = (f32x4){0.f, 0.f, 0.f, 0.f};
    }
    #pragma unroll
    for (int kc = 0; kc < 2; ++kc) {
      bf16x8 a[4];
      #pragma unroll
      for (int nt2 = 0; nt2 < 4; ++nt2)
        a[nt2] = *(const bf16x8*)&lds_aw[(nt2 * 16 + l15) * 72 + kc * 32 + l4 * 8];
      const char* gp = (const char*)lds_x + (kc * 32 + l4 * 8) * 536 + (te0 * 16 + l15) * 2;
      #pragma unroll
      for (int j = 0; j < 2; ++j) {
        union { unsigned short u[8]; bf16x8 v; } bb;   // transposed gather of x
        #pragma unroll
        for (int i = 0; i < 8; ++i)
          bb.u[i] = *(const unsigned short*)(gp + i * 536 + j * 32);
        #pragma unroll
        for (int nt2 = 0; nt2 < 4; ++nt2)
          acc[nt2][j] = __builtin_amdgcn_mfma_f32_16x16x32_bf16(a[nt2], bb.v, acc[nt2][j], 0, 0, 0);
      }
    }
    float* ob = out + (size_t)b * 16384;
    #pragma unroll
    for (int nt2 = 0; nt2 < 4; ++nt2)
      #pragma unroll
      for (int j = 0; j < 2; ++j)
        #pragma unroll
        for (int r = 0; r < 4; ++r)
          ob[(nt2 * 16 + 4 * l4 + r) * 256 + (te0 + j) * 16 + l15] = __expf(acc[nt2][j][r]);
  }
}

extern "C" void kernel_launch(void* const* d_in, const int* in_sizes, int n_in,
                              void* d_out, int out_size, void* d_ws, size_t ws_size,
                              hipStream_t stream) {
  const float* x     = (const float*)d_in[0];
  const float* W     = (const float*)d_in[1];
  const float* q     = (const float*)d_in[2];
  const float* value = (const float*)d_in[3];
  float* out = (float*)d_out;
  unsigned short* qw = (unsigned short*)d_ws;  // 64*256 bf16 = 32 KB scratch

  qw_kernel<<<dim3(64), dim3(256), 0, stream>>>(q, W, qw);
  cross_main<<<dim3(2048), dim3(512), 0, stream>>>(x, value, qw, out);
}